// Round 12
// baseline (104.447 us; speedup 1.0000x reference)
//
#include <hip/hip_runtime.h>
#include <math.h>

namespace {

constexpr int SPW  = 8;     // real samples per wave (MFMA M=16, rows 8..15 padded)
constexpr int ACTW = 196;   // act row stride (floats): 196 mod 32 = 4 -> ~2-way banks
constexpr float LNEPS = 1e-5f;

typedef __attribute__((ext_vector_type(8))) __bf16 bf16x8;
typedef __attribute__((ext_vector_type(4))) float  f32x4;

template<int V> struct ic { static constexpr int value = V; };

template<int N, int I = 0, class F>
__device__ __forceinline__ void sfor(F&& f) {
    if constexpr (I < N) { f(ic<I>{}); sfor<N, I + 1>(f); }
}

__device__ __forceinline__ float elu1(float v) {
    return v > 0.f ? v : (__expf(v) - 1.f);
}

// Single fused kernel: 2 waves/block, 1 block/CU.
// Each block converts fp32 weights -> bf16 MFMA B-fragments in LDS itself
// (no pack kernel, no d_ws): frag ff, lane l, elem e holds
//   W[kt*32 + 8*(l>>4) + e][nt*16 + (l&15)]
// Frag map in wlds: 0..31 gat0 | 32..63 gat1 | 64..111 W1 | 112..127 W2.
// Wp's 8 fragments live in registers (direct strided fp32 loads at entry).
__global__ __launch_bounds__(128) void mfma_fused(
    const float* __restrict__ x, const int* __restrict__ sid,
    const float* __restrict__ Wp, const float* __restrict__ bp,
    const float* __restrict__ emb, const float* __restrict__ gatW,
    const float* __restrict__ W1, const float* __restrict__ b1,
    const float* __restrict__ g1, const float* __restrict__ be1,
    const float* __restrict__ W2, const float* __restrict__ b2,
    const float* __restrict__ g2, const float* __restrict__ be2,
    const float* __restrict__ Wo, const float* __restrict__ bo,
    float* __restrict__ out)
{
    __shared__ __align__(16) __bf16 wlds[128 * 512];      // 131072 B
    __shared__ __align__(16) float  actbuf[2][16 * ACTW]; //  25088 B (156160 total)

    const int tid = threadIdx.x;
    const int l   = tid & 63;
    const int w   = tid >> 6;        // wave 0/1
    const int gq  = l >> 4;          // lane group 0..3
    const int j   = l & 15;          // MFMA col / A-row residue
    const int sbase = (blockIdx.x * 2 + w) * SPW;
    float* A = actbuf[w];

    // ---- entry loads (issue early; latency hides under frag staging) ----
    const int s  = l >> 2, ch = l & 3;
    float4 xv0 = {0,0,0,0}, xv1 = xv0;
    int st = 0;
    if (s < SPW) {
        const float* xp = x + (size_t)(sbase + s) * 32 + ch * 8;
        xv0 = *reinterpret_cast<const float4*>(xp);
        xv1 = *reinterpret_cast<const float4*>(xp + 4);
        st  = sid[sbase + s];
    }
    // Wp fragments straight from fp32 global (rows (l>>4)*8+e, col nt*16+j)
    bf16x8 wpf[8];
    {
        const float* wp0 = Wp + (size_t)(gq * 8) * 128 + j;
        sfor<8>([&](auto NT) {
            bf16x8 v;
            sfor<8>([&](auto E) {
                v[E.value] = (__bf16)wp0[(size_t)E.value * 128 + NT.value * 16];
            });
            wpf[NT.value] = v;
        });
    }
    float bpv[8];
    sfor<8>([&](auto NT) { bpv[NT.value] = bp[NT.value * 16 + j]; });

    // ---- stage 128 weight frags fp32->bf16 into LDS ----
    // wave 0: frags 0..63 (gat0, gat1); wave 1: frags 64..127 (W1, W2)
    {
        const int lhi = (l >> 4) * 8, llo = l & 15;
        if (w == 0) {
#pragma unroll 4
            for (int ff = 0; ff < 64; ++ff) {
                const int layer = ff >> 5;          // 0: gat0, 1: gat1
                const int kt = (ff >> 3) & 3, nt = ff & 7;
                const float* src = gatW + (size_t)layer * 16384
                                 + (size_t)(kt * 32 + lhi) * 128 + nt * 16 + llo;
                bf16x8 v;
                sfor<8>([&](auto E) { v[E.value] = (__bf16)src[E.value * 128]; });
                *reinterpret_cast<bf16x8*>(wlds + ((size_t)ff * 64 + l) * 8) = v;
            }
        } else {
#pragma unroll 4
            for (int i = 0; i < 48; ++i) {          // W1: K=192, 6 kt x 8 nt
                const int kt = i >> 3, nt = i & 7;
                const float* src = W1 + (size_t)(kt * 32 + lhi) * 128 + nt * 16 + llo;
                bf16x8 v;
                sfor<8>([&](auto E) { v[E.value] = (__bf16)src[E.value * 128]; });
                *reinterpret_cast<bf16x8*>(wlds + ((size_t)(64 + i) * 64 + l) * 8) = v;
            }
#pragma unroll 4
            for (int r = 0; r < 16; ++r) {          // W2: K=128, 4 kt x 4 nt, N=64
                const int kt = r >> 2, nt = r & 3;
                const float* src = W2 + (size_t)(kt * 32 + lhi) * 64 + nt * 16 + llo;
                bf16x8 v;
                sfor<8>([&](auto E) { v[E.value] = (__bf16)src[E.value * 64]; });
                *reinterpret_cast<bf16x8*>(wlds + ((size_t)(112 + r) * 64 + l) * 8) = v;
            }
        }
    }

    // ---- stage x rows (pad rows zero) + emb cols 128..191 ----
    {
        float* dst = A + s * ACTW + ch * 8;
        *reinterpret_cast<float4*>(dst)     = xv0;
        *reinterpret_cast<float4*>(dst + 4) = xv1;
        float4 e0 = {0,0,0,0}, e1 = e0, e2 = e0, e3 = e0;
        if (s < SPW) {
            const float* ep = emb + (size_t)st * 64 + ch * 16;
            e0 = *reinterpret_cast<const float4*>(ep);
            e1 = *reinterpret_cast<const float4*>(ep + 4);
            e2 = *reinterpret_cast<const float4*>(ep + 8);
            e3 = *reinterpret_cast<const float4*>(ep + 12);
        }
        float* ed = A + s * ACTW + 128 + ch * 16;
        *reinterpret_cast<float4*>(ed)      = e0;
        *reinterpret_cast<float4*>(ed + 4)  = e1;
        *reinterpret_cast<float4*>(ed + 8)  = e2;
        *reinterpret_cast<float4*>(ed + 12) = e3;
    }
    __syncthreads();   // weights staged; act is wave-local

    // A-fragment fetch: lane reads its 8 k-values of row j, converts to bf16
    auto akt = [&]<int KT>(ic<KT>) -> bf16x8 {
        const float* p = A + j * ACTW + KT * 32 + gq * 8;
        const float4 f0 = *reinterpret_cast<const float4*>(p);
        const float4 f1 = *reinterpret_cast<const float4*>(p + 4);
        bf16x8 a;
        a[0] = (__bf16)f0.x; a[1] = (__bf16)f0.y; a[2] = (__bf16)f0.z; a[3] = (__bf16)f0.w;
        a[4] = (__bf16)f1.x; a[5] = (__bf16)f1.y; a[6] = (__bf16)f1.z; a[7] = (__bf16)f1.w;
        return a;
    };

    // GEMM with B-fragments from LDS (conflict-free linear reads, 1-deep prefetch)
    auto gemm = [&]<int NKT, int NNT>(ic<NKT>, ic<NNT>, int fbase, f32x4 (&acc)[NNT]) {
        const __bf16* fb = wlds + (size_t)fbase * 512 + (size_t)l * 8;
        bf16x8 bq0[NNT], bq1[NNT];
        auto ldkt = [&](auto KT, bf16x8 (&bq)[NNT]) {
            sfor<NNT>([&](auto NT) {
                bq[NT.value] = *reinterpret_cast<const bf16x8*>(
                    fb + (size_t)(decltype(KT)::value * NNT + NT.value) * 512);
            });
        };
        auto mm = [&](bf16x8 a, bf16x8 (&bq)[NNT]) {
            sfor<NNT>([&](auto NT) {
                acc[NT.value] = __builtin_amdgcn_mfma_f32_16x16x32_bf16(
                    a, bq[NT.value], acc[NT.value], 0, 0, 0);
            });
        };
        ldkt(ic<0>{}, bq0);
        sfor<NKT>([&](auto KT) {
            constexpr int kt = decltype(KT)::value;
            if constexpr (kt + 1 < NKT) {
                if constexpr (((kt + 1) & 1) == 0) ldkt(ic<kt + 1>{}, bq0);
                else                               ldkt(ic<kt + 1>{}, bq1);
            }
            const bf16x8 a = akt(ic<kt>{});
            if constexpr ((kt & 1) == 0) mm(a, bq0); else mm(a, bq1);
        });
    };

    // write C regs back to act rows (row = 4*gq + r, col = nt*16 + j)
    auto writeC = [&](f32x4 (&C)[8]) {
        sfor<8>([&](auto NT) { sfor<4>([&](auto R) {
            A[(4 * gq + R.value) * ACTW + NT.value * 16 + j] = C[NT.value][R.value];
        }); });
    };

    f32x4 hC[8];

    // ---- Wp: h0 = x @ Wp + bp  (register frags) ----
    {
        f32x4 acc[8] = {};
        const bf16x8 a = akt(ic<0>{});
        sfor<8>([&](auto NT) {
            acc[NT.value] = __builtin_amdgcn_mfma_f32_16x16x32_bf16(
                a, wpf[NT.value], acc[NT.value], 0, 0, 0);
        });
        sfor<8>([&](auto NT) { sfor<4>([&](auto R) {
            hC[NT.value][R.value] = acc[NT.value][R.value] + bpv[NT.value];
        }); });
    }
    writeC(hC);

    // ---- GAT0: h += elu(h @ gW0) ----
    {
        f32x4 acc[8] = {};
        gemm(ic<4>{}, ic<8>{}, 0, acc);
        sfor<8>([&](auto NT) { sfor<4>([&](auto R) {
            hC[NT.value][R.value] += elu1(acc[NT.value][R.value]);
        }); });
    }
    writeC(hC);

    // ---- GAT1: h += elu(h @ gW1) ----
    {
        f32x4 acc[8] = {};
        gemm(ic<4>{}, ic<8>{}, 32, acc);
        sfor<8>([&](auto NT) { sfor<4>([&](auto R) {
            hC[NT.value][R.value] += elu1(acc[NT.value][R.value]);
        }); });
    }
    writeC(hC);

    // ---- W1: u = [h, emb] @ W1 + b1 ; LN1 + relu -> act cols 0..127 ----
    {
        f32x4 acc[8] = {};
        gemm(ic<6>{}, ic<8>{}, 64, acc);
        float b1v[8], g1v[8], be1v[8];
        sfor<8>([&](auto NT) {
            b1v[NT.value]  = b1[NT.value * 16 + j];
            g1v[NT.value]  = g1[NT.value * 16 + j];
            be1v[NT.value] = be1[NT.value * 16 + j];
        });
        float su[4] = {}, sq[4] = {};
        sfor<8>([&](auto NT) { sfor<4>([&](auto R) {
            const float u = acc[NT.value][R.value] + b1v[NT.value];
            acc[NT.value][R.value] = u;
            su[R.value] += u; sq[R.value] += u * u;
        }); });
#pragma unroll
        for (int off = 1; off <= 8; off <<= 1) {
            sfor<4>([&](auto R) {
                su[R.value] += __shfl_xor(su[R.value], off, 64);
                sq[R.value] += __shfl_xor(sq[R.value], off, 64);
            });
        }
        float m[4], rs[4];
        sfor<4>([&](auto R) {
            m[R.value] = su[R.value] * (1.f / 128.f);
            const float var = sq[R.value] * (1.f / 128.f) - m[R.value] * m[R.value];
            rs[R.value] = rsqrtf(var + LNEPS);
        });
        sfor<8>([&](auto NT) { sfor<4>([&](auto R) {
            const float z = fmaxf((acc[NT.value][R.value] - m[R.value]) * rs[R.value]
                                  * g1v[NT.value] + be1v[NT.value], 0.f);
            A[(4 * gq + R.value) * ACTW + NT.value * 16 + j] = z;
        }); });
    }

    // ---- W2: v = z1 @ W2 + b2 ; LN2 + relu ; out = z2 @ Wo + bo ----
    {
        f32x4 acc[4] = {};
        gemm(ic<4>{}, ic<4>{}, 112, acc);
        float b2v[4], g2v[4], be2v[4], wov[4];
        sfor<4>([&](auto NT) {
            b2v[NT.value]  = b2[NT.value * 16 + j];
            g2v[NT.value]  = g2[NT.value * 16 + j];
            be2v[NT.value] = be2[NT.value * 16 + j];
            wov[NT.value]  = Wo[NT.value * 16 + j];
        });
        float su[4] = {}, sq[4] = {};
        sfor<4>([&](auto NT) { sfor<4>([&](auto R) {
            const float v = acc[NT.value][R.value] + b2v[NT.value];
            acc[NT.value][R.value] = v;
            su[R.value] += v; sq[R.value] += v * v;
        }); });
#pragma unroll
        for (int off = 1; off <= 8; off <<= 1) {
            sfor<4>([&](auto R) {
                su[R.value] += __shfl_xor(su[R.value], off, 64);
                sq[R.value] += __shfl_xor(sq[R.value], off, 64);
            });
        }
        float po[4];
        sfor<4>([&](auto R) {
            const float m   = su[R.value] * (1.f / 64.f);
            const float var = sq[R.value] * (1.f / 64.f) - m * m;
            const float rs  = rsqrtf(var + LNEPS);
            float p = 0.f;
            sfor<4>([&](auto NT) {
                p += fmaxf((acc[NT.value][R.value] - m) * rs * g2v[NT.value]
                           + be2v[NT.value], 0.f) * wov[NT.value];
            });
            po[R.value] = p;
        });
#pragma unroll
        for (int off = 1; off <= 8; off <<= 1) {
            sfor<4>([&](auto R) { po[R.value] += __shfl_xor(po[R.value], off, 64); });
        }
        const float bov = bo[0];
        if (j == 0 && gq < 2) {
            sfor<4>([&](auto R) {
                out[sbase + 4 * gq + R.value] = po[R.value] + bov;
            });
        }
    }
}

}  // namespace

extern "C" void kernel_launch(void* const* d_in, const int* in_sizes, int n_in,
                              void* d_out, int out_size, void* d_ws, size_t ws_size,
                              hipStream_t stream)
{
    const float* x    = (const float*)d_in[0];
    const int*   sid  = (const int*)d_in[1];
    // d_in[2] edge_index, d_in[3] edge_weight, d_in[8] gat_a: unused —
    // node-uniform broadcast + row-softmax makes the GAT aggregation collapse
    // to elu(h @ W) independent of the graph.
    const float* Wp   = (const float*)d_in[4];
    const float* bp   = (const float*)d_in[5];
    const float* emb  = (const float*)d_in[6];
    const float* gatW = (const float*)d_in[7];
    const float* W1   = (const float*)d_in[9];
    const float* b1   = (const float*)d_in[10];
    const float* g1   = (const float*)d_in[11];
    const float* be1  = (const float*)d_in[12];
    const float* W2   = (const float*)d_in[13];
    const float* b2   = (const float*)d_in[14];
    const float* g2   = (const float*)d_in[15];
    const float* be2  = (const float*)d_in[16];
    const float* Wo   = (const float*)d_in[17];
    const float* bo   = (const float*)d_in[18];
    float* out = (float*)d_out;

    // Single kernel node: 256 blocks x 2 waves (1 block/CU), weights staged
    // fp32->bf16 fragments in-block (no pack kernel, no d_ws round trip).
    mfma_fused<<<dim3(4096 / (2 * SPW)), dim3(128), 0, stream>>>(
        x, sid, Wp, bp, emb, gatW, W1, b1, g1, be1,
        W2, b2, g2, be2, Wo, bo, out);
}

// Round 13
// 101.244 us; speedup vs baseline: 1.0316x; 1.0316x over previous
//
#include <hip/hip_runtime.h>
#include <math.h>

namespace {

constexpr int SPW  = 4;     // real samples per wave (MFMA M=16, rows 4..15 padded)
constexpr int ACTW = 196;   // act row stride (floats)
constexpr float LNEPS = 1e-5f;

typedef __attribute__((ext_vector_type(8))) __bf16 bf16x8;
typedef __attribute__((ext_vector_type(4))) float  f32x4;

template<int V> struct ic { static constexpr int value = V; };

template<int N, int I = 0, class F>
__device__ __forceinline__ void sfor(F&& f) {
    if constexpr (I < N) { f(ic<I>{}); sfor<N, I + 1>(f); }
}

__device__ __forceinline__ float elu1(float v) {
    return v > 0.f ? v : (__expf(v) - 1.f);
}

// ---------------- weight pack kernel (r9, verified) ----------------
// Frag f (0..135), lane l holds W[kt*32 + 8*(l>>4) + e][nt*16 + (l&15)], e=0..7,
// as bf16x8 at wsf + (f*64 + l)*8.  Frag map:
//   0..7 Wp | 8..39 gat0 | 40..71 gat1 | 72..119 W1 | 120..135 W2
__global__ __launch_bounds__(64) void pack_weights(
    const float* __restrict__ Wp, const float* __restrict__ gatW,
    const float* __restrict__ W1, const float* __restrict__ W2,
    __bf16* __restrict__ wsf)
{
    const int f = blockIdx.x;
    const int l = threadIdx.x;
    const float* src; int kt, nt, N;
    if (f < 8)        { src = Wp;            kt = 0;            nt = f;            N = 128; }
    else if (f < 40)  { int r = f - 8;  src = gatW;         kt = r >> 3; nt = r & 7; N = 128; }
    else if (f < 72)  { int r = f - 40; src = gatW + 16384; kt = r >> 3; nt = r & 7; N = 128; }
    else if (f < 120) { int r = f - 72; src = W1;           kt = r / 8;  nt = r % 8; N = 128; }
    else              { int r = f - 120; src = W2;          kt = r >> 2; nt = r & 3; N = 64;  }
    const int k0 = kt * 32 + (l >> 4) * 8;
    const int n  = nt * 16 + (l & 15);
    bf16x8 v;
    sfor<8>([&](auto E) {
        v[E.value] = (__bf16)src[(size_t)(k0 + E.value) * N + n];
    });
    *reinterpret_cast<bf16x8*>(wsf + ((size_t)f * 64 + l) * 8) = v;
}

// ---------------- main fused kernel (small-code: runtime loops) ----------------
__global__ __launch_bounds__(64) void mfma_fused(
    const float* __restrict__ x, const int* __restrict__ sid,
    const __bf16* __restrict__ wsf,
    const float* __restrict__ bp, const float* __restrict__ emb,
    const float* __restrict__ b1, const float* __restrict__ g1,
    const float* __restrict__ be1,
    const float* __restrict__ b2, const float* __restrict__ g2,
    const float* __restrict__ be2,
    const float* __restrict__ Wo, const float* __restrict__ bo,
    float* __restrict__ out)
{
    __shared__ __align__(16) float A[16 * ACTW];   // 12544 B -> several blocks/CU

    const int l  = threadIdx.x;
    const int gq = l >> 4;      // lane group 0..3
    const int j  = l & 15;      // MFMA col / A-row residue
    const int sbase = blockIdx.x * SPW;

    // ---- entry loads ----
    const int s = l >> 2, ch = l & 3;
    float4 xv0 = {0,0,0,0}, xv1 = xv0;
    int st = 0;
    if (s < SPW) {
        const float* xp = x + (size_t)(sbase + s) * 32 + ch * 8;
        xv0 = *reinterpret_cast<const float4*>(xp);
        xv1 = *reinterpret_cast<const float4*>(xp + 4);
        st  = sid[sbase + s];
    }
    bf16x8 wpf[8];
    sfor<8>([&](auto NT) {
        wpf[NT.value] = *reinterpret_cast<const bf16x8*>(
            wsf + ((size_t)NT.value * 64 + l) * 8);
    });
    float bpv[8];
    sfor<8>([&](auto NT) { bpv[NT.value] = bp[NT.value * 16 + j]; });

    // ---- stage x rows (pad rows zero) + emb cols 128..191 ----
    {
        float* dst = A + s * ACTW + ch * 8;
        *reinterpret_cast<float4*>(dst)     = xv0;
        *reinterpret_cast<float4*>(dst + 4) = xv1;
        float4 e0 = {0,0,0,0}, e1 = e0, e2 = e0, e3 = e0;
        if (s < SPW) {
            const float* ep = emb + (size_t)st * 64 + ch * 16;
            e0 = *reinterpret_cast<const float4*>(ep);
            e1 = *reinterpret_cast<const float4*>(ep + 4);
            e2 = *reinterpret_cast<const float4*>(ep + 8);
            e3 = *reinterpret_cast<const float4*>(ep + 12);
        }
        float* ed = A + s * ACTW + 128 + ch * 16;
        *reinterpret_cast<float4*>(ed)      = e0;
        *reinterpret_cast<float4*>(ed + 4)  = e1;
        *reinterpret_cast<float4*>(ed + 8)  = e2;
        *reinterpret_cast<float4*>(ed + 12) = e3;
    }
    // single wave: in-order DS pipe orders write->read; no barrier needed

    // A-fragment fetch (runtime kt)
    auto aktd = [&](int kt) -> bf16x8 {
        const float* p = A + j * ACTW + kt * 32 + gq * 8;
        const float4 f0 = *reinterpret_cast<const float4*>(p);
        const float4 f1 = *reinterpret_cast<const float4*>(p + 4);
        bf16x8 a;
        a[0] = (__bf16)f0.x; a[1] = (__bf16)f0.y; a[2] = (__bf16)f0.z; a[3] = (__bf16)f0.w;
        a[4] = (__bf16)f1.x; a[5] = (__bf16)f1.y; a[6] = (__bf16)f1.z; a[7] = (__bf16)f1.w;
        return a;
    };

    // GEMM: runtime kt loop (kept rolled), static NT unroll, 2-deep bq pipeline
    auto gemm = [&]<int NNT>(ic<NNT>, int nkt, int fbase, f32x4 (&acc)[NNT]) {
        asm volatile("" : "+s"(nkt));   // launder trip count: keep loop rolled
        const __bf16* fb = wsf + ((size_t)fbase * 64 + l) * 8;
        bf16x8 bq0[NNT], bq1[NNT];
        auto ld = [&](int kt, bf16x8 (&bq)[NNT]) {
            const __bf16* p = fb + (size_t)kt * (NNT * 512);
            sfor<NNT>([&](auto NT) {
                bq[NT.value] = *reinterpret_cast<const bf16x8*>(p + NT.value * 512);
            });
        };
        auto mm = [&](bf16x8 a, bf16x8 (&bq)[NNT]) {
            sfor<NNT>([&](auto NT) {
                acc[NT.value] = __builtin_amdgcn_mfma_f32_16x16x32_bf16(
                    a, bq[NT.value], acc[NT.value], 0, 0, 0);
            });
        };
        ld(0, bq0);
#pragma clang loop unroll(disable)
        for (int kt = 0; kt < nkt; kt += 2) {
            ld(kt + 1, bq1);
            mm(aktd(kt), bq0);
            if (kt + 2 < nkt) ld(kt + 2, bq0);
            mm(aktd(kt + 1), bq1);
        }
    };

    // write C regs back to act rows (row = 4*gq + r, col = nt*16 + j)
    auto writeC = [&](f32x4 (&C)[8]) {
        sfor<8>([&](auto NT) { sfor<4>([&](auto R) {
            A[(4 * gq + R.value) * ACTW + NT.value * 16 + j] = C[NT.value][R.value];
        }); });
    };

    f32x4 hC[8];

    // ---- Wp: h0 = x @ Wp + bp (register frags, single kt) ----
    {
        f32x4 acc[8] = {};
        const bf16x8 a = aktd(0);
        sfor<8>([&](auto NT) {
            acc[NT.value] = __builtin_amdgcn_mfma_f32_16x16x32_bf16(
                a, wpf[NT.value], acc[NT.value], 0, 0, 0);
        });
        sfor<8>([&](auto NT) { sfor<4>([&](auto R) {
            hC[NT.value][R.value] = acc[NT.value][R.value] + bpv[NT.value];
        }); });
    }
    writeC(hC);

    // ---- GAT x2 (rolled layer loop): h += elu(h @ gWi) ----
    {
        int ngat = 2;
        asm volatile("" : "+s"(ngat));
#pragma clang loop unroll(disable)
        for (int gi = 0; gi < ngat; ++gi) {
            f32x4 acc[8] = {};
            gemm(ic<8>{}, 4, 8 + gi * 32, acc);
            sfor<8>([&](auto NT) { sfor<4>([&](auto R) {
                hC[NT.value][R.value] += elu1(acc[NT.value][R.value]);
            }); });
            writeC(hC);
        }
    }

    // ---- W1: u = [h, emb] @ W1 + b1 ; LN1 + relu -> act cols 0..127 ----
    {
        f32x4 acc[8] = {};
        gemm(ic<8>{}, 6, 72, acc);
        float b1v[8], g1v[8], be1v[8];
        sfor<8>([&](auto NT) {
            b1v[NT.value]  = b1[NT.value * 16 + j];
            g1v[NT.value]  = g1[NT.value * 16 + j];
            be1v[NT.value] = be1[NT.value * 16 + j];
        });
        float su[4] = {}, sq[4] = {};
        sfor<8>([&](auto NT) { sfor<4>([&](auto R) {
            const float u = acc[NT.value][R.value] + b1v[NT.value];
            acc[NT.value][R.value] = u;
            su[R.value] += u; sq[R.value] += u * u;
        }); });
#pragma unroll
        for (int off = 1; off <= 8; off <<= 1) {
            sfor<4>([&](auto R) {
                su[R.value] += __shfl_xor(su[R.value], off, 64);
                sq[R.value] += __shfl_xor(sq[R.value], off, 64);
            });
        }
        float m[4], rs[4];
        sfor<4>([&](auto R) {
            m[R.value] = su[R.value] * (1.f / 128.f);
            const float var = sq[R.value] * (1.f / 128.f) - m[R.value] * m[R.value];
            rs[R.value] = rsqrtf(var + LNEPS);
        });
        sfor<8>([&](auto NT) { sfor<4>([&](auto R) {
            const float z = fmaxf((acc[NT.value][R.value] - m[R.value]) * rs[R.value]
                                  * g1v[NT.value] + be1v[NT.value], 0.f);
            A[(4 * gq + R.value) * ACTW + NT.value * 16 + j] = z;
        }); });
    }

    // ---- W2: v = z1 @ W2 + b2 ; LN2 + relu ; out = z2 @ Wo + bo ----
    {
        f32x4 acc[4] = {};
        gemm(ic<4>{}, 4, 120, acc);
        float b2v[4], g2v[4], be2v[4], wov[4];
        sfor<4>([&](auto NT) {
            b2v[NT.value]  = b2[NT.value * 16 + j];
            g2v[NT.value]  = g2[NT.value * 16 + j];
            be2v[NT.value] = be2[NT.value * 16 + j];
            wov[NT.value]  = Wo[NT.value * 16 + j];
        });
        float su[4] = {}, sq[4] = {};
        sfor<4>([&](auto NT) { sfor<4>([&](auto R) {
            const float v = acc[NT.value][R.value] + b2v[NT.value];
            acc[NT.value][R.value] = v;
            su[R.value] += v; sq[R.value] += v * v;
        }); });
#pragma unroll
        for (int off = 1; off <= 8; off <<= 1) {
            sfor<4>([&](auto R) {
                su[R.value] += __shfl_xor(su[R.value], off, 64);
                sq[R.value] += __shfl_xor(sq[R.value], off, 64);
            });
        }
        float po[4];
        sfor<4>([&](auto R) {
            const float m   = su[R.value] * (1.f / 64.f);
            const float var = sq[R.value] * (1.f / 64.f) - m * m;
            const float rs  = rsqrtf(var + LNEPS);
            float p = 0.f;
            sfor<4>([&](auto NT) {
                p += fmaxf((acc[NT.value][R.value] - m) * rs * g2v[NT.value]
                           + be2v[NT.value], 0.f) * wov[NT.value];
            });
            po[R.value] = p;
        });
#pragma unroll
        for (int off = 1; off <= 8; off <<= 1) {
            sfor<4>([&](auto R) { po[R.value] += __shfl_xor(po[R.value], off, 64); });
        }
        const float bov = bo[0];
        if (j == 0 && gq == 0) {           // rows 0..3 = the SPW real samples
            sfor<4>([&](auto R) {
                out[sbase + R.value] = po[R.value] + bov;
            });
        }
    }
}

}  // namespace

extern "C" void kernel_launch(void* const* d_in, const int* in_sizes, int n_in,
                              void* d_out, int out_size, void* d_ws, size_t ws_size,
                              hipStream_t stream)
{
    const float* x    = (const float*)d_in[0];
    const int*   sid  = (const int*)d_in[1];
    // d_in[2] edge_index, d_in[3] edge_weight, d_in[8] gat_a: unused —
    // node-uniform broadcast + row-softmax makes the GAT aggregation collapse
    // to elu(h @ W) independent of the graph.
    const float* Wp   = (const float*)d_in[4];
    const float* bp   = (const float*)d_in[5];
    const float* emb  = (const float*)d_in[6];
    const float* gatW = (const float*)d_in[7];
    const float* W1   = (const float*)d_in[9];
    const float* b1   = (const float*)d_in[10];
    const float* g1   = (const float*)d_in[11];
    const float* be1  = (const float*)d_in[12];
    const float* W2   = (const float*)d_in[13];
    const float* b2   = (const float*)d_in[14];
    const float* g2   = (const float*)d_in[15];
    const float* be2  = (const float*)d_in[16];
    const float* Wo   = (const float*)d_in[17];
    const float* bo   = (const float*)d_in[18];
    float* out = (float*)d_out;

    __bf16* wsf = (__bf16*)d_ws;   // 136 frags * 1024 B = 139264 B << ws_size

    // 1) repack weights into per-lane MFMA B-fragments (bf16, RNE)
    pack_weights<<<dim3(136), dim3(64), 0, stream>>>(Wp, gatW, W1, W2, wsf);
    // 2) fused forward: 1024 single-wave blocks (SPW=4) -> 4 blocks/CU,
    //    small I$-resident code (rolled kt / layer loops)
    mfma_fused<<<dim3(4096 / SPW), dim3(64), 0, stream>>>(
        x, sid, wsf, bp, emb, b1, g1, be1, b2, g2, be2, Wo, bo, out);
}